// Round 1
// baseline (2792.562 us; speedup 1.0000x reference)
//
#include <hip/hip_runtime.h>
#include <cstddef>
#include <cstdint>

// ---------------------------------------------------------------------------
// Mamba forward. T = B*L = 4096 tokens. D_MODEL=1024, D_INNER=2048,
// DT_RANK=64, N_STATE=16, V2=32002.
//
// gemm_head (83% of FLOPs) now runs on MFMA via 3-term bf16 split
// (ah*bh + ah*bl + al*bh), ~17 mantissa bits => ~1e-5 rel error.
//
// Workspace layout (floats), total 46,530,560 floats = 186.1 MB:
//   phase 1 (through gemm_mout):
//     xz   [4096 x 4096]   at 0          16,777,216
//     xc   [4096 x 2048]   at 16,777,216  8,388,608
//     dbl  [4096 x 96]     at 25,165,824    393,216
//     dt   [4096 x 2048]   at 25,559,040  8,388,608
//     y    [4096 x 2048]   at 33,947,648  8,388,608
//     mo   [4096 x 1024]   at 42,336,256  4,194,304
//   phase 2 (after gemm_mout; aliases xz..y which are then dead):
//     Wt_hi ushort[32128 x 1024] at float-ofs 0          (16,449,536 fl)
//     Wt_lo ushort[32128 x 1024] at float-ofs 16,449,536
//     mo_hi ushort[4096 x 1024]  at float-ofs 32,899,072 ( 2,097,152 fl)
//     mo_lo ushort[4096 x 1024]  at float-ofs 34,996,224 (ends 37,093,376)
//     mo (fp32) at 42,336,256 still live.
// ---------------------------------------------------------------------------

typedef __bf16 bf16x8 __attribute__((ext_vector_type(8)));
typedef float f32x4 __attribute__((ext_vector_type(4)));

__device__ __forceinline__ float sigmoidf_(float x) {
  return 1.0f / (1.0f + __expf(-x));
}

__device__ __forceinline__ unsigned short f2bf(float v) {
  unsigned u = __float_as_uint(v);
  u += 0x7fffu + ((u >> 16) & 1u);
  return (unsigned short)(u >> 16);
}
__device__ __forceinline__ float bf2f(unsigned short h) {
  return __uint_as_float(((unsigned)h) << 16);
}

// async global->LDS, 16B per lane. LDS dest must be linear in lane (it is:
// our staging offset is tid*16B within each 256-thread chunk).
__device__ __forceinline__ void gload_lds16(const void* g, void* l) {
  typedef const unsigned int GQ __attribute__((address_space(1)));
  typedef unsigned int LQ __attribute__((address_space(3)));
  __builtin_amdgcn_global_load_lds((GQ*)(unsigned long long)g,
                                   (LQ*)(unsigned)(unsigned long long)l,
                                   16, 0, 0);
}

// ---------------- GEMM: xz = emb[x] @ W_in   M=4096 K=1024 N=4096 ----------
__global__ __launch_bounds__(256) void gemm_xz_kernel(
    const int* __restrict__ x, const float* __restrict__ emb,
    const float* __restrict__ W, float* __restrict__ out) {
  __shared__ float As[16][68];
  __shared__ float Bs[16][68];
  const int tid = threadIdx.x;
  const int tx = tid & 15, ty = tid >> 4;
  const int m0 = blockIdx.y * 64, n0 = blockIdx.x * 64;
  const int am = tid >> 2, ak = (tid & 3) * 4;
  const int bk = tid >> 4, bn = (tid & 15) * 4;
  const int row = x[m0 + am];
  const float* aptr = emb + (size_t)row * 1024 + ak;
  const float* bptr = W + (size_t)bk * 4096 + n0 + bn;
  float acc[4][4] = {};
  float4 av = *(const float4*)(aptr);
  float4 bv = *(const float4*)(bptr);
  for (int k0 = 0; k0 < 1024; k0 += 16) {
    __syncthreads();
    As[ak + 0][am] = av.x; As[ak + 1][am] = av.y;
    As[ak + 2][am] = av.z; As[ak + 3][am] = av.w;
    *(float4*)&Bs[bk][bn] = bv;
    __syncthreads();
    if (k0 + 16 < 1024) {
      av = *(const float4*)(aptr + k0 + 16);
      bv = *(const float4*)(bptr + (size_t)(k0 + 16) * 4096);
    }
#pragma unroll
    for (int kk = 0; kk < 16; ++kk) {
      float4 a = *(const float4*)&As[kk][ty * 4];
      float4 b = *(const float4*)&Bs[kk][tx * 4];
      float aa[4] = {a.x, a.y, a.z, a.w};
      float bb[4] = {b.x, b.y, b.z, b.w};
#pragma unroll
      for (int i = 0; i < 4; ++i)
#pragma unroll
        for (int j = 0; j < 4; ++j)
          acc[i][j] = fmaf(aa[i], bb[j], acc[i][j]);
    }
  }
#pragma unroll
  for (int i = 0; i < 4; ++i) {
    float4 v = make_float4(acc[i][0], acc[i][1], acc[i][2], acc[i][3]);
    *(float4*)(out + (size_t)(m0 + ty * 4 + i) * 4096 + n0 + tx * 4) = v;
  }
}

// ---------------- depthwise causal conv (taps=4) + SiLU --------------------
__global__ __launch_bounds__(256) void conv_silu_kernel(
    const float* __restrict__ xz, const float* __restrict__ conv_w,
    const float* __restrict__ conv_b, float* __restrict__ xc) {
  const int idx = blockIdx.x * 256 + threadIdx.x;  // t*2048 + d
  const int t = idx >> 11, d = idx & 2047;
  const int l = t & 2047;
  const float4 w = *(const float4*)(conv_w + (size_t)d * 4);
  const float ww[4] = {w.x, w.y, w.z, w.w};
  float s = conv_b[d];
  const float* xm = xz + d;
#pragma unroll
  for (int j = 0; j < 4; ++j) {
    int lj = l - 3 + j;
    if (lj >= 0) s = fmaf(ww[j], xm[(size_t)(t - 3 + j) * 4096], s);
  }
  xc[idx] = s * sigmoidf_(s);
}

// ---------------- dbl = xc @ W_x   M=4096 K=2048 N=96 ----------------------
__global__ __launch_bounds__(256) void gemm_dbl_kernel(
    const float* __restrict__ xc, const float* __restrict__ Wx,
    float* __restrict__ dbl) {
  const int idx = blockIdx.x * 256 + threadIdx.x;
  const int tq = idx / 96, c = idx % 96;
  const size_t t0 = (size_t)tq * 4;
  const float* a0 = xc + t0 * 2048;
  float acc[4] = {0.f, 0.f, 0.f, 0.f};
  for (int k = 0; k < 2048; k += 4) {
    float w0 = Wx[(size_t)(k + 0) * 96 + c];
    float w1 = Wx[(size_t)(k + 1) * 96 + c];
    float w2 = Wx[(size_t)(k + 2) * 96 + c];
    float w3 = Wx[(size_t)(k + 3) * 96 + c];
#pragma unroll
    for (int i = 0; i < 4; ++i) {
      float4 avv = *(const float4*)(a0 + (size_t)i * 2048 + k);
      acc[i] = fmaf(avv.x, w0, acc[i]);
      acc[i] = fmaf(avv.y, w1, acc[i]);
      acc[i] = fmaf(avv.z, w2, acc[i]);
      acc[i] = fmaf(avv.w, w3, acc[i]);
    }
  }
#pragma unroll
  for (int i = 0; i < 4; ++i) dbl[(t0 + i) * 96 + c] = acc[i];
}

// ---------------- dt = softplus(dt_r @ W_dt + b_dt)  K=64 N=2048 -----------
__global__ __launch_bounds__(256) void gemm_dt_kernel(
    const float* __restrict__ dbl, const float* __restrict__ Wdt,
    const float* __restrict__ b_dt, float* __restrict__ dt) {
  __shared__ float s[4][64];
  const int t0 = (blockIdx.x >> 3) * 4;
  const int d = ((blockIdx.x & 7) << 8) + threadIdx.x;
  {
    int tt = threadIdx.x >> 6, k = threadIdx.x & 63;
    s[tt][k] = dbl[(size_t)(t0 + tt) * 96 + k];
  }
  __syncthreads();
  const float bd = b_dt[d];
  float acc[4] = {bd, bd, bd, bd};
#pragma unroll 16
  for (int k = 0; k < 64; ++k) {
    float w = Wdt[(size_t)k * 2048 + d];
#pragma unroll
    for (int i = 0; i < 4; ++i) acc[i] = fmaf(s[i][k], w, acc[i]);
  }
#pragma unroll
  for (int i = 0; i < 4; ++i) {
    float v = acc[i];
    float sp = (v > 20.f) ? v : log1pf(__expf(v));
    dt[(size_t)(t0 + i) * 2048 + d] = sp;
  }
}

// ---------------- selective scan -------------------------------------------
__global__ __launch_bounds__(256) void scan_kernel(
    const float* __restrict__ dt, const float* __restrict__ xc,
    const float* __restrict__ dbl, const float* __restrict__ A_log,
    float* __restrict__ y) {
  const int tid = threadIdx.x;
  const int n = tid & 15;
  const int dloc = tid >> 4;
  const int b = blockIdx.x >> 7;
  const int d = ((blockIdx.x & 127) << 4) + dloc;
  const float A = -__expf(A_log[(size_t)d * 16 + n]);
  float h = 0.f;
  const size_t tb = (size_t)b * 2048;
  const float* dtp = dt + tb * 2048 + d;
  const float* xcp = xc + tb * 2048 + d;
  const float* Bp = dbl + tb * 96 + 64 + n;
  const float* Cp = dbl + tb * 96 + 80 + n;
  float* yo = y + tb * 2048 + d;

  constexpr int CH = 8;
  float cdt[CH], cx[CH], cB[CH], cC[CH];
#pragma unroll
  for (int j = 0; j < CH; ++j) {
    cdt[j] = dtp[(size_t)j * 2048];
    cx[j] = xcp[(size_t)j * 2048];
    cB[j] = Bp[(size_t)j * 96];
    cC[j] = Cp[(size_t)j * 96];
  }
  for (int t0 = 0; t0 < 2048; t0 += CH) {
    float ndt[CH], nx[CH], nB[CH], nC[CH];
    const bool more = (t0 + CH < 2048);
    if (more) {
#pragma unroll
      for (int j = 0; j < CH; ++j) {
        size_t o = (size_t)(t0 + CH + j);
        ndt[j] = dtp[o * 2048];
        nx[j] = xcp[o * 2048];
        nB[j] = Bp[o * 96];
        nC[j] = Cp[o * 96];
      }
    }
#pragma unroll
    for (int j = 0; j < CH; ++j) {
      float dA = __expf(cdt[j] * A);
      h = fmaf(dA, h, cdt[j] * cx[j] * cB[j]);
      float p = h * cC[j];
      p += __shfl_xor(p, 1);
      p += __shfl_xor(p, 2);
      p += __shfl_xor(p, 4);
      p += __shfl_xor(p, 8);
      if (n == 0) yo[(size_t)(t0 + j) * 2048] = p;
    }
    if (more) {
#pragma unroll
      for (int j = 0; j < CH; ++j) {
        cdt[j] = ndt[j]; cx[j] = nx[j]; cB[j] = nB[j]; cC[j] = nC[j];
      }
    }
  }
}

// ---------------- y = (y + xc*D) * silu(z), in place -----------------------
__global__ __launch_bounds__(256) void ypost_kernel(
    float* __restrict__ y, const float* __restrict__ xc,
    const float* __restrict__ xz, const float* __restrict__ Dskip) {
  const size_t idx = ((size_t)blockIdx.x * 256 + threadIdx.x) * 4;
  const size_t t = idx >> 11;
  const int d = (int)(idx & 2047);
  float4 yv = *(float4*)(y + idx);
  float4 xv = *(const float4*)(xc + idx);
  float4 zv = *(const float4*)(xz + t * 4096 + 2048 + d);
  float4 Dv = *(const float4*)(Dskip + d);
  float yy[4] = {yv.x, yv.y, yv.z, yv.w};
  float xx[4] = {xv.x, xv.y, xv.z, xv.w};
  float zz[4] = {zv.x, zv.y, zv.z, zv.w};
  float dd[4] = {Dv.x, Dv.y, Dv.z, Dv.w};
  float r[4];
#pragma unroll
  for (int i = 0; i < 4; ++i) {
    float t1 = fmaf(xx[i], dd[i], yy[i]);
    r[i] = t1 * (zz[i] * sigmoidf_(zz[i]));
  }
  *(float4*)(y + idx) = make_float4(r[0], r[1], r[2], r[3]);
}

// ---------------- GEMM: mo = y @ W_out   M=4096 K=2048 N=1024 --------------
__global__ __launch_bounds__(256) void gemm_mout_kernel(
    const float* __restrict__ Ain, const float* __restrict__ W,
    float* __restrict__ out) {
  __shared__ float As[16][68];
  __shared__ float Bs[16][68];
  const int tid = threadIdx.x;
  const int tx = tid & 15, ty = tid >> 4;
  const int m0 = blockIdx.y * 64, n0 = blockIdx.x * 64;
  const int am = tid >> 2, ak = (tid & 3) * 4;
  const int bk = tid >> 4, bn = (tid & 15) * 4;
  const float* aptr = Ain + (size_t)(m0 + am) * 2048 + ak;
  const float* bptr = W + (size_t)bk * 1024 + n0 + bn;
  float acc[4][4] = {};
  float4 av = *(const float4*)(aptr);
  float4 bv = *(const float4*)(bptr);
  for (int k0 = 0; k0 < 2048; k0 += 16) {
    __syncthreads();
    As[ak + 0][am] = av.x; As[ak + 1][am] = av.y;
    As[ak + 2][am] = av.z; As[ak + 3][am] = av.w;
    *(float4*)&Bs[bk][bn] = bv;
    __syncthreads();
    if (k0 + 16 < 2048) {
      av = *(const float4*)(aptr + k0 + 16);
      bv = *(const float4*)(bptr + (size_t)(k0 + 16) * 1024);
    }
#pragma unroll
    for (int kk = 0; kk < 16; ++kk) {
      float4 a = *(const float4*)&As[kk][ty * 4];
      float4 b = *(const float4*)&Bs[kk][tx * 4];
      float aa[4] = {a.x, a.y, a.z, a.w};
      float bb[4] = {b.x, b.y, b.z, b.w};
#pragma unroll
      for (int i = 0; i < 4; ++i)
#pragma unroll
        for (int j = 0; j < 4; ++j)
          acc[i][j] = fmaf(aa[i], bb[j], acc[i][j]);
    }
  }
#pragma unroll
  for (int i = 0; i < 4; ++i) {
    float4 v = make_float4(acc[i][0], acc[i][1], acc[i][2], acc[i][3]);
    *(float4*)(out + (size_t)(m0 + ty * 4 + i) * 1024 + n0 + tx * 4) = v;
  }
}

// ---------------- split W_head: transpose + bf16 hi/lo + swizzle -----------
// W [1024][32002] -> Wt_hi/Wt_lo [32128][1024] (rows >= 32002 zeroed).
// k-index within each 32-elem chunk has its 8-elem sub-block XOR'd with
// key(n) = (n>>1)&3 so that linear global_load_lds staging + XOR'd ds_read
// in the GEMM is ~2-way bank-conflict-free.
__global__ __launch_bounds__(256) void split_w_kernel(
    const float* __restrict__ W, unsigned short* __restrict__ Whi,
    unsigned short* __restrict__ Wlo) {
  __shared__ float tile[64][65];
  const int kb = blockIdx.x & 15;   // 16 k-tiles of 64
  const int nb = blockIdx.x >> 4;   // 502 n-tiles of 64
  const int k0 = kb * 64, n0 = nb * 64;
  const int tq = threadIdx.x >> 6;  // 0..3
  const int tl = threadIdx.x & 63;  // 0..63
#pragma unroll
  for (int r = 0; r < 16; ++r) {
    int kk = r * 4 + tq;
    int n = n0 + tl;
    tile[kk][tl] = (n < 32002) ? W[(size_t)(k0 + kk) * 32002 + n] : 0.f;
  }
  __syncthreads();
#pragma unroll
  for (int r = 0; r < 16; ++r) {
    int nn = r * 4 + tq;
    int n = n0 + nn;
    int k = k0 + tl;
    float v = tile[tl][nn];
    unsigned short h = f2bf(v);
    unsigned short l = f2bf(v - bf2f(h));
    int key = (n >> 1) & 3;
    size_t o = (size_t)n * 1024 + (size_t)(k & ~31) +
               (size_t)(((((k >> 3) & 3) ^ key)) << 3) + (size_t)(k & 7);
    Whi[o] = h;
    Wlo[o] = l;
  }
}

// ---------------- split mo: bf16 hi/lo + swizzle ---------------------------
__global__ __launch_bounds__(256) void split_mo_kernel(
    const float* __restrict__ mo, unsigned short* __restrict__ mhi,
    unsigned short* __restrict__ mlo) {
  const int i = blockIdx.x * 256 + threadIdx.x;  // < 524288
  const int t = i >> 7;
  const int sb = i & 127;  // 8-elem block within row
  const float* src = mo + (size_t)t * 1024 + (size_t)sb * 8;
  float4 v0 = *(const float4*)(src);
  float4 v1 = *(const float4*)(src + 4);
  float vv[8] = {v0.x, v0.y, v0.z, v0.w, v1.x, v1.y, v1.z, v1.w};
  unsigned hu[4], lu[4];
#pragma unroll
  for (int j = 0; j < 4; ++j) {
    unsigned short h0 = f2bf(vv[2 * j]), h1 = f2bf(vv[2 * j + 1]);
    unsigned short l0 = f2bf(vv[2 * j] - bf2f(h0));
    unsigned short l1 = f2bf(vv[2 * j + 1] - bf2f(h1));
    hu[j] = (unsigned)h0 | ((unsigned)h1 << 16);
    lu[j] = (unsigned)l0 | ((unsigned)l1 << 16);
  }
  const int key = (t >> 1) & 3;
  const int sdst = (sb & 3) ^ key;
  size_t o = (size_t)t * 1024 + (size_t)(sb >> 2) * 32 + (size_t)sdst * 8;
  *(uint4*)(mhi + o) = make_uint4(hu[0], hu[1], hu[2], hu[3]);
  *(uint4*)(mlo + o) = make_uint4(lu[0], lu[1], lu[2], lu[3]);
}

// ---------------- MFMA GEMM head: out[b][n][l] = mo @ W_head + b -----------
// D[n][t] orientation: A = W^T (Wt arrays), B = mo^T (mo arrays, k-contig).
// 128x128 tile, BK=32, 4 waves x (4x4) 16x16x32 fragments, 3-term bf16 split.
__global__ __launch_bounds__(256, 2) void gemm_head_mfma_kernel(
    const unsigned short* __restrict__ Whi, const unsigned short* __restrict__ Wlo,
    const unsigned short* __restrict__ mhi, const unsigned short* __restrict__ mlo,
    const float* __restrict__ bias, float* __restrict__ out) {
  __shared__ unsigned short Ah[4096], Al[4096], Bh[4096], Bl[4096];  // 32 KB
  const int tid = threadIdx.x;
  const int lane = tid & 63, wid = tid >> 6;
  const int wr = wid >> 1, wc = wid & 1;
  // XCD-chunked swizzle: 8032 blocks = 8 * 1004; t-tile fastest within chunk.
  const int swz = ((blockIdx.x & 7) * 1004) + (blockIdx.x >> 3);
  const int n0 = (swz >> 5) * 128;  // vocab-row base (padded to 32128)
  const int t0 = (swz & 31) * 128;  // token base

  // staging: 512 chunks of 16B per tile; thread handles chunks tid, tid+256.
  // LDS elem offset = chunk*8 -> linear in (wave-uniform base + lane*16B). OK.
  const int c0 = tid, c1 = tid + 256;
  const int r0 = c0 >> 2, s0 = (c0 & 3) * 8;
  const int r1 = c1 >> 2, s1 = (c1 & 3) * 8;
  const unsigned short* pA0h = Whi + (size_t)(n0 + r0) * 1024 + s0;
  const unsigned short* pA0l = Wlo + (size_t)(n0 + r0) * 1024 + s0;
  const unsigned short* pB0h = mhi + (size_t)(t0 + r0) * 1024 + s0;
  const unsigned short* pB0l = mlo + (size_t)(t0 + r0) * 1024 + s0;
  const unsigned short* pA1h = Whi + (size_t)(n0 + r1) * 1024 + s1;
  const unsigned short* pA1l = Wlo + (size_t)(n0 + r1) * 1024 + s1;
  const unsigned short* pB1h = mhi + (size_t)(t0 + r1) * 1024 + s1;
  const unsigned short* pB1l = mlo + (size_t)(t0 + r1) * 1024 + s1;
  unsigned short* lA0 = Ah + c0 * 8;
  unsigned short* lA1 = Ah + c1 * 8;
  unsigned short* lAl0 = Al + c0 * 8;
  unsigned short* lAl1 = Al + c1 * 8;
  unsigned short* lB0 = Bh + c0 * 8;
  unsigned short* lB1 = Bh + c1 * 8;
  unsigned short* lBl0 = Bl + c0 * 8;
  unsigned short* lBl1 = Bl + c1 * 8;

#define STAGE_HEAD(KOFF)                  \
  do {                                    \
    gload_lds16(pA0h + (KOFF), lA0);      \
    gload_lds16(pA1h + (KOFF), lA1);      \
    gload_lds16(pA0l + (KOFF), lAl0);     \
    gload_lds16(pA1l + (KOFF), lAl1);     \
    gload_lds16(pB0h + (KOFF), lB0);      \
    gload_lds16(pB1h + (KOFF), lB1);      \
    gload_lds16(pB0l + (KOFF), lBl0);     \
    gload_lds16(pB1l + (KOFF), lBl1);     \
  } while (0)

  // fragment LDS offsets (loop-invariant; XOR matches the pre-swizzle)
  const int fr = lane & 15;
  const int kb = (lane >> 4) * 8;
  int aoff[4], boff[4];
#pragma unroll
  for (int m = 0; m < 4; ++m) {
    int r = 64 * wr + 16 * m + fr;
    aoff[m] = r * 32 + (kb ^ (((r >> 1) & 3) << 3));
  }
#pragma unroll
  for (int nf = 0; nf < 4; ++nf) {
    int r = 64 * wc + 16 * nf + fr;
    boff[nf] = r * 32 + (kb ^ (((r >> 1) & 3) << 3));
  }

  f32x4 acc[4][4];
#pragma unroll
  for (int m = 0; m < 4; ++m)
#pragma unroll
    for (int nf = 0; nf < 4; ++nf) acc[m][nf] = f32x4{0.f, 0.f, 0.f, 0.f};

  STAGE_HEAD(0);
  int koff = 32;
  for (int ks = 0; ks < 32; ++ks) {
    __syncthreads();  // vmcnt(0) drained -> staged tile visible
    bf16x8 ah[4], al[4], bh[4], bl[4];
#pragma unroll
    for (int m = 0; m < 4; ++m) {
      ah[m] = *(const bf16x8*)(Ah + aoff[m]);
      al[m] = *(const bf16x8*)(Al + aoff[m]);
    }
#pragma unroll
    for (int nf = 0; nf < 4; ++nf) {
      bh[nf] = *(const bf16x8*)(Bh + boff[nf]);
      bl[nf] = *(const bf16x8*)(Bl + boff[nf]);
    }
    __syncthreads();  // all waves' ds_reads done -> safe to overwrite
    if (ks < 31) {
      STAGE_HEAD(koff);  // async loads fly during the MFMA cluster
      koff += 32;
    }
#pragma unroll
    for (int m = 0; m < 4; ++m)
#pragma unroll
      for (int nf = 0; nf < 4; ++nf) {
        acc[m][nf] = __builtin_amdgcn_mfma_f32_16x16x32_bf16(
            ah[m], bh[nf], acc[m][nf], 0, 0, 0);
        acc[m][nf] = __builtin_amdgcn_mfma_f32_16x16x32_bf16(
            ah[m], bl[nf], acc[m][nf], 0, 0, 0);
        acc[m][nf] = __builtin_amdgcn_mfma_f32_16x16x32_bf16(
            al[m], bh[nf], acc[m][nf], 0, 0, 0);
      }
  }
#undef STAGE_HEAD

  // epilogue: D row = vocab n, D col = token t. col=lane&15, row=4*(l>>4)+r.
  const int frow = 4 * (lane >> 4);
#pragma unroll
  for (int m = 0; m < 4; ++m) {
    const int gn_base = n0 + 64 * wr + 16 * m + frow;
#pragma unroll
    for (int r = 0; r < 4; ++r) {
      const int gn = gn_base + r;
      if (gn < 32002) {
        const float bb = bias[gn];
#pragma unroll
        for (int nf = 0; nf < 4; ++nf) {
          const int gt = t0 + 64 * wc + 16 * nf + fr;
          const int b_idx = gt >> 11;
          const int l = gt & 2047;
          out[((size_t)b_idx * 32002 + gn) * 2048 + l] = acc[m][nf][r] + bb;
        }
      }
    }
  }
}

// ---------------------------------------------------------------------------
extern "C" void kernel_launch(void* const* d_in, const int* in_sizes, int n_in,
                              void* d_out, int out_size, void* d_ws,
                              size_t ws_size, hipStream_t stream) {
  const int* x = (const int*)d_in[0];
  const float* emb = (const float*)d_in[1];
  const float* W_in = (const float*)d_in[2];
  const float* conv_w = (const float*)d_in[3];
  const float* conv_b = (const float*)d_in[4];
  const float* W_x = (const float*)d_in[5];
  const float* W_dt = (const float*)d_in[6];
  const float* b_dt = (const float*)d_in[7];
  const float* A_log = (const float*)d_in[8];
  const float* D_skip = (const float*)d_in[9];
  const float* W_out = (const float*)d_in[10];
  const float* W_head = (const float*)d_in[11];
  const float* b_head = (const float*)d_in[12];
  float* out = (float*)d_out;

  float* ws = (float*)d_ws;
  // phase-1 buffers
  float* xz = ws;                    // 16,777,216
  float* xc = xz + 16777216;         //  8,388,608
  float* dbl = xc + 8388608;         //    393,216
  float* dt = dbl + 393216;          //  8,388,608
  float* y = dt + 8388608;           //  8,388,608
  float* mo = y + 8388608;           //  4,194,304
  // phase-2 buffers (alias xz..y; first touched after gemm_mout)
  unsigned short* Wt_hi = (unsigned short*)ws;               // 32128x1024
  unsigned short* Wt_lo = (unsigned short*)(ws + 16449536);  // 32128x1024
  unsigned short* mo_hi = (unsigned short*)(ws + 32899072);  // 4096x1024
  unsigned short* mo_lo = (unsigned short*)(ws + 34996224);  // 4096x1024

  dim3 blk(256);
  gemm_xz_kernel<<<dim3(64, 64), blk, 0, stream>>>(x, emb, W_in, xz);
  conv_silu_kernel<<<32768, blk, 0, stream>>>(xz, conv_w, conv_b, xc);
  gemm_dbl_kernel<<<384, blk, 0, stream>>>(xc, W_x, dbl);
  gemm_dt_kernel<<<8192, blk, 0, stream>>>(dbl, W_dt, b_dt, dt);
  scan_kernel<<<256, blk, 0, stream>>>(dt, xc, dbl, A_log, y);
  ypost_kernel<<<8192, blk, 0, stream>>>(y, xc, xz, D_skip);
  gemm_mout_kernel<<<dim3(16, 64), blk, 0, stream>>>(y, W_out, mo);
  split_w_kernel<<<8032, blk, 0, stream>>>(W_head, Wt_hi, Wt_lo);
  split_mo_kernel<<<2048, blk, 0, stream>>>(mo, mo_hi, mo_lo);
  gemm_head_mfma_kernel<<<8032, blk, 0, stream>>>(Wt_hi, Wt_lo, mo_hi, mo_lo,
                                                  b_head, out);
}

// Round 2
// 2333.282 us; speedup vs baseline: 1.1968x; 1.1968x over previous
//
#include <hip/hip_runtime.h>
#include <cstddef>
#include <cstdint>

// ---------------------------------------------------------------------------
// Mamba forward. T = B*L = 4096 tokens. D_MODEL=1024, D_INNER=2048,
// DT_RANK=64, N_STATE=16, V2=32002.
//
// All three large GEMMs (xz, mout, head = 99% of FLOPs) run on MFMA via
// 3-term bf16 split (ah*bh + ah*bl + al*bh), ~17 mantissa bits.
//
// Workspace (floats), total 46,530,560 = 186.1 MB, lifetime-aliased:
//   xz   [4096x4096] fp32 @ 0            (dead after ypost; then WoT, then Wt)
//   xc   [4096x2048] fp32 @ 16,777,216   (dead after ypost)
//   dbl  [4096x96]   fp32 @ 25,165,824   (dead after scan; then yh)
//   dt   [4096x2048] fp32 @ 25,559,040   (dead after scan; then yl)
//   y    [4096x2048] fp32 @ 33,947,648   (tok/WiT before scan; mo_hi/lo after)
//   mo   [4096x1024] fp32 @ 42,336,256
// phase A (before scan writes y):
//   tokh/tokl ushort[4096x1024] @ 33,947,648 / 36,044,800
//   WiTh/WiTl ushort[4096x1024] @ 38,141,952 / 40,239,104
// phase C (after scan):
//   yh/yl     ushort[4096x2048] @ 25,165,824 / 29,360,128
//   WoTh/WoTl ushort[1024x2048] @ 0 / 1,048,576
// phase E (after mout):
//   Wt_hi/Wt_lo ushort[32128x1024] @ 0 / 16,449,536
//   mo_hi/mo_lo ushort[4096x1024]  @ 32,899,072 / 34,996,224
// ---------------------------------------------------------------------------

typedef __bf16 bf16x8 __attribute__((ext_vector_type(8)));
typedef float f32x4 __attribute__((ext_vector_type(4)));

__device__ __forceinline__ float sigmoidf_(float x) {
  return 1.0f / (1.0f + __expf(-x));
}

__device__ __forceinline__ unsigned short f2bf(float v) {
  unsigned u = __float_as_uint(v);
  u += 0x7fffu + ((u >> 16) & 1u);
  return (unsigned short)(u >> 16);
}
__device__ __forceinline__ float bf2f(unsigned short h) {
  return __uint_as_float(((unsigned)h) << 16);
}

__device__ __forceinline__ void gload_lds16(const void* g, void* l) {
  typedef const unsigned int GQ __attribute__((address_space(1)));
  typedef unsigned int LQ __attribute__((address_space(3)));
  __builtin_amdgcn_global_load_lds((GQ*)(unsigned long long)g,
                                   (LQ*)(unsigned)(unsigned long long)l,
                                   16, 0, 0);
}

// ---------------- generic: W [K][Nreal] -> hi/lo [Npad][K] swizzled --------
// grid = dim3(K/64, Npad/64). Pre-swizzle: within each 32-elem k-chunk the
// 8-elem sub-block index is XOR'd with key(n) = (n>>1)&3 (matches the GEMM's
// ds_read XOR so LDS reads are ~conflict-free with linear global_load_lds).
__global__ __launch_bounds__(256) void split_wT_kernel(
    const float* __restrict__ W, int Nreal, unsigned short* __restrict__ hi,
    unsigned short* __restrict__ lo, int K) {
  __shared__ float tile[64][65];
  const int k0 = blockIdx.x * 64, n0 = blockIdx.y * 64;
  const int tq = threadIdx.x >> 6;  // 0..3
  const int tl = threadIdx.x & 63;  // 0..63
#pragma unroll
  for (int r = 0; r < 16; ++r) {
    int kk = r * 4 + tq;
    int n = n0 + tl;
    tile[kk][tl] = (n < Nreal) ? W[(size_t)(k0 + kk) * Nreal + n] : 0.f;
  }
  __syncthreads();
#pragma unroll
  for (int r = 0; r < 16; ++r) {
    int nn = r * 4 + tq;
    int n = n0 + nn;
    int k = k0 + tl;
    float v = tile[tl][nn];
    unsigned short h = f2bf(v);
    unsigned short l = f2bf(v - bf2f(h));
    int key = (n >> 1) & 3;
    size_t o = (size_t)n * K + (size_t)(k & ~31) +
               (size_t)(((((k >> 3) & 3) ^ key)) << 3) + (size_t)(k & 7);
    hi[o] = h;
    lo[o] = l;
  }
}

// ---------------- token gather + bf16 split + swizzle ----------------------
__global__ __launch_bounds__(256) void tok_split_kernel(
    const int* __restrict__ x, const float* __restrict__ emb,
    unsigned short* __restrict__ th, unsigned short* __restrict__ tlo) {
  const int i = blockIdx.x * 256 + threadIdx.x;  // < 524288
  const int t = i >> 7;
  const int sb = i & 127;
  const int row = x[t];
  const float* src = emb + (size_t)row * 1024 + (size_t)sb * 8;
  float4 v0 = *(const float4*)(src);
  float4 v1 = *(const float4*)(src + 4);
  float vv[8] = {v0.x, v0.y, v0.z, v0.w, v1.x, v1.y, v1.z, v1.w};
  unsigned hu[4], lu[4];
#pragma unroll
  for (int j = 0; j < 4; ++j) {
    unsigned short h0 = f2bf(vv[2 * j]), h1 = f2bf(vv[2 * j + 1]);
    unsigned short l0 = f2bf(vv[2 * j] - bf2f(h0));
    unsigned short l1 = f2bf(vv[2 * j + 1] - bf2f(h1));
    hu[j] = (unsigned)h0 | ((unsigned)h1 << 16);
    lu[j] = (unsigned)l0 | ((unsigned)l1 << 16);
  }
  const int key = (t >> 1) & 3;
  const int sdst = (sb & 3) ^ key;
  size_t o = (size_t)t * 1024 + (size_t)(sb >> 2) * 32 + (size_t)sdst * 8;
  *(uint4*)(th + o) = make_uint4(hu[0], hu[1], hu[2], hu[3]);
  *(uint4*)(tlo + o) = make_uint4(lu[0], lu[1], lu[2], lu[3]);
}

// ---------------- split mo: bf16 hi/lo + swizzle ---------------------------
__global__ __launch_bounds__(256) void split_mo_kernel(
    const float* __restrict__ mo, unsigned short* __restrict__ mhi,
    unsigned short* __restrict__ mlo) {
  const int i = blockIdx.x * 256 + threadIdx.x;  // < 524288
  const int t = i >> 7;
  const int sb = i & 127;
  const float* src = mo + (size_t)t * 1024 + (size_t)sb * 8;
  float4 v0 = *(const float4*)(src);
  float4 v1 = *(const float4*)(src + 4);
  float vv[8] = {v0.x, v0.y, v0.z, v0.w, v1.x, v1.y, v1.z, v1.w};
  unsigned hu[4], lu[4];
#pragma unroll
  for (int j = 0; j < 4; ++j) {
    unsigned short h0 = f2bf(vv[2 * j]), h1 = f2bf(vv[2 * j + 1]);
    unsigned short l0 = f2bf(vv[2 * j] - bf2f(h0));
    unsigned short l1 = f2bf(vv[2 * j + 1] - bf2f(h1));
    hu[j] = (unsigned)h0 | ((unsigned)h1 << 16);
    lu[j] = (unsigned)l0 | ((unsigned)l1 << 16);
  }
  const int key = (t >> 1) & 3;
  const int sdst = (sb & 3) ^ key;
  size_t o = (size_t)t * 1024 + (size_t)(sb >> 2) * 32 + (size_t)sdst * 8;
  *(uint4*)(mhi + o) = make_uint4(hu[0], hu[1], hu[2], hu[3]);
  *(uint4*)(mlo + o) = make_uint4(lu[0], lu[1], lu[2], lu[3]);
}

// ---------------- generic MFMA GEMM, 3-term bf16 split ---------------------
// D[row][col] = sum_k A[row][k]*B[col][k]; A rows from R0, B rows from C0.
// 128x128 tile, BK=32, 4 waves x (4x4) 16x16x32 fragments.
// OUTMODE 0: out[row*ldo + col] fp32, no bias, no guard.
// OUTMODE 1: head layout out[((col>>11)*32002 + row)*2048 + (col&2047)],
//            guard row<32002, +bias[row].
template <int K, int OUTMODE, int BT>
__global__ __launch_bounds__(256, 2) void gemm_mfma_kernel(
    const unsigned short* __restrict__ Ah_, const unsigned short* __restrict__ Al_,
    const unsigned short* __restrict__ Bh_, const unsigned short* __restrict__ Bl_,
    const float* __restrict__ bias, float* __restrict__ out, int ldo) {
  __shared__ unsigned short Ah[4096], Al[4096], Bh[4096], Bl[4096];  // 32 KB
  const int tid = threadIdx.x;
  const int lane = tid & 63, wid = tid >> 6;
  const int wr = wid >> 1, wc = wid & 1;
  // XCD-chunked bijective swizzle (grid % 8 == 0 for all instances)
  const int chunk = (int)gridDim.x >> 3;
  const int swz = ((blockIdx.x & 7) * chunk) + (blockIdx.x >> 3);
  const int R0 = (swz / BT) * 128;  // A-row tile base
  const int C0 = (swz % BT) * 128;  // B-row tile base

  const int c0 = tid, c1 = tid + 256;
  const int r0 = c0 >> 2, s0 = (c0 & 3) * 8;
  const int r1 = c1 >> 2, s1 = (c1 & 3) * 8;
  const unsigned short* pA0h = Ah_ + (size_t)(R0 + r0) * K + s0;
  const unsigned short* pA0l = Al_ + (size_t)(R0 + r0) * K + s0;
  const unsigned short* pB0h = Bh_ + (size_t)(C0 + r0) * K + s0;
  const unsigned short* pB0l = Bl_ + (size_t)(C0 + r0) * K + s0;
  const unsigned short* pA1h = Ah_ + (size_t)(R0 + r1) * K + s1;
  const unsigned short* pA1l = Al_ + (size_t)(R0 + r1) * K + s1;
  const unsigned short* pB1h = Bh_ + (size_t)(C0 + r1) * K + s1;
  const unsigned short* pB1l = Bl_ + (size_t)(C0 + r1) * K + s1;
  unsigned short* lA0 = Ah + c0 * 8;
  unsigned short* lA1 = Ah + c1 * 8;
  unsigned short* lAl0 = Al + c0 * 8;
  unsigned short* lAl1 = Al + c1 * 8;
  unsigned short* lB0 = Bh + c0 * 8;
  unsigned short* lB1 = Bh + c1 * 8;
  unsigned short* lBl0 = Bl + c0 * 8;
  unsigned short* lBl1 = Bl + c1 * 8;

#define STAGE_T(KOFF)                 \
  do {                                \
    gload_lds16(pA0h + (KOFF), lA0);  \
    gload_lds16(pA1h + (KOFF), lA1);  \
    gload_lds16(pA0l + (KOFF), lAl0); \
    gload_lds16(pA1l + (KOFF), lAl1); \
    gload_lds16(pB0h + (KOFF), lB0);  \
    gload_lds16(pB1h + (KOFF), lB1);  \
    gload_lds16(pB0l + (KOFF), lBl0); \
    gload_lds16(pB1l + (KOFF), lBl1); \
  } while (0)

  const int fr = lane & 15;
  const int kb = (lane >> 4) * 8;
  int aoff[4], boff[4];
#pragma unroll
  for (int m = 0; m < 4; ++m) {
    int r = 64 * wr + 16 * m + fr;
    aoff[m] = r * 32 + (kb ^ (((r >> 1) & 3) << 3));
  }
#pragma unroll
  for (int nf = 0; nf < 4; ++nf) {
    int r = 64 * wc + 16 * nf + fr;
    boff[nf] = r * 32 + (kb ^ (((r >> 1) & 3) << 3));
  }

  f32x4 acc[4][4];
#pragma unroll
  for (int m = 0; m < 4; ++m)
#pragma unroll
    for (int nf = 0; nf < 4; ++nf) acc[m][nf] = f32x4{0.f, 0.f, 0.f, 0.f};

  STAGE_T(0);
  int koff = 32;
  constexpr int KSTEPS = K / 32;
  for (int ks = 0; ks < KSTEPS; ++ks) {
    __syncthreads();
    bf16x8 ah[4], al[4], bh[4], bl[4];
#pragma unroll
    for (int m = 0; m < 4; ++m) {
      ah[m] = *(const bf16x8*)(Ah + aoff[m]);
      al[m] = *(const bf16x8*)(Al + aoff[m]);
    }
#pragma unroll
    for (int nf = 0; nf < 4; ++nf) {
      bh[nf] = *(const bf16x8*)(Bh + boff[nf]);
      bl[nf] = *(const bf16x8*)(Bl + boff[nf]);
    }
    __syncthreads();
    if (ks < KSTEPS - 1) {
      STAGE_T(koff);
      koff += 32;
    }
#pragma unroll
    for (int m = 0; m < 4; ++m)
#pragma unroll
      for (int nf = 0; nf < 4; ++nf) {
        acc[m][nf] = __builtin_amdgcn_mfma_f32_16x16x32_bf16(
            ah[m], bh[nf], acc[m][nf], 0, 0, 0);
        acc[m][nf] = __builtin_amdgcn_mfma_f32_16x16x32_bf16(
            ah[m], bl[nf], acc[m][nf], 0, 0, 0);
        acc[m][nf] = __builtin_amdgcn_mfma_f32_16x16x32_bf16(
            al[m], bh[nf], acc[m][nf], 0, 0, 0);
      }
  }
#undef STAGE_T

  // C/D layout (verified): col = lane&15 (B rows), row = 4*(lane>>4)+reg (A).
  const int frow = 4 * (lane >> 4);
#pragma unroll
  for (int m = 0; m < 4; ++m) {
    const int gr_base = R0 + 64 * wr + 16 * m + frow;
#pragma unroll
    for (int r = 0; r < 4; ++r) {
      const int gr = gr_base + r;
      if constexpr (OUTMODE == 1) {
        if (gr < 32002) {
          const float bb = bias[gr];
#pragma unroll
          for (int nf = 0; nf < 4; ++nf) {
            const int gc = C0 + 64 * wc + 16 * nf + fr;
            const int b_idx = gc >> 11;
            const int l = gc & 2047;
            out[((size_t)b_idx * 32002 + gr) * 2048 + l] = acc[m][nf][r] + bb;
          }
        }
      } else {
#pragma unroll
        for (int nf = 0; nf < 4; ++nf) {
          const int gc = C0 + 64 * wc + 16 * nf + fr;
          out[(size_t)gr * ldo + gc] = acc[m][nf][r];
        }
      }
    }
  }
}

// ---------------- depthwise causal conv (taps=4) + SiLU --------------------
__global__ __launch_bounds__(256) void conv_silu_kernel(
    const float* __restrict__ xz, const float* __restrict__ conv_w,
    const float* __restrict__ conv_b, float* __restrict__ xc) {
  const int idx = blockIdx.x * 256 + threadIdx.x;  // t*2048 + d
  const int t = idx >> 11, d = idx & 2047;
  const int l = t & 2047;
  const float4 w = *(const float4*)(conv_w + (size_t)d * 4);
  const float ww[4] = {w.x, w.y, w.z, w.w};
  float s = conv_b[d];
  const float* xm = xz + d;
#pragma unroll
  for (int j = 0; j < 4; ++j) {
    int lj = l - 3 + j;
    if (lj >= 0) s = fmaf(ww[j], xm[(size_t)(t - 3 + j) * 4096], s);
  }
  xc[idx] = s * sigmoidf_(s);
}

// ---------------- dbl = xc @ W_x   M=4096 K=2048 N=96 ----------------------
__global__ __launch_bounds__(256) void gemm_dbl_kernel(
    const float* __restrict__ xc, const float* __restrict__ Wx,
    float* __restrict__ dbl) {
  const int idx = blockIdx.x * 256 + threadIdx.x;
  const int tq = idx / 96, c = idx % 96;
  const size_t t0 = (size_t)tq * 4;
  const float* a0 = xc + t0 * 2048;
  float acc[4] = {0.f, 0.f, 0.f, 0.f};
  for (int k = 0; k < 2048; k += 4) {
    float w0 = Wx[(size_t)(k + 0) * 96 + c];
    float w1 = Wx[(size_t)(k + 1) * 96 + c];
    float w2 = Wx[(size_t)(k + 2) * 96 + c];
    float w3 = Wx[(size_t)(k + 3) * 96 + c];
#pragma unroll
    for (int i = 0; i < 4; ++i) {
      float4 avv = *(const float4*)(a0 + (size_t)i * 2048 + k);
      acc[i] = fmaf(avv.x, w0, acc[i]);
      acc[i] = fmaf(avv.y, w1, acc[i]);
      acc[i] = fmaf(avv.z, w2, acc[i]);
      acc[i] = fmaf(avv.w, w3, acc[i]);
    }
  }
#pragma unroll
  for (int i = 0; i < 4; ++i) dbl[(t0 + i) * 96 + c] = acc[i];
}

// ---------------- dt = softplus(dt_r @ W_dt + b_dt)  K=64 N=2048 -----------
__global__ __launch_bounds__(256) void gemm_dt_kernel(
    const float* __restrict__ dbl, const float* __restrict__ Wdt,
    const float* __restrict__ b_dt, float* __restrict__ dt) {
  __shared__ float s[4][64];
  const int t0 = (blockIdx.x >> 3) * 4;
  const int d = ((blockIdx.x & 7) << 8) + threadIdx.x;
  {
    int tt = threadIdx.x >> 6, k = threadIdx.x & 63;
    s[tt][k] = dbl[(size_t)(t0 + tt) * 96 + k];
  }
  __syncthreads();
  const float bd = b_dt[d];
  float acc[4] = {bd, bd, bd, bd};
#pragma unroll 16
  for (int k = 0; k < 64; ++k) {
    float w = Wdt[(size_t)k * 2048 + d];
#pragma unroll
    for (int i = 0; i < 4; ++i) acc[i] = fmaf(s[i][k], w, acc[i]);
  }
#pragma unroll
  for (int i = 0; i < 4; ++i) {
    float v = acc[i];
    float sp = (v > 20.f) ? v : log1pf(__expf(v));
    dt[(size_t)(t0 + i) * 2048 + d] = sp;
  }
}

// ---------------- selective scan -------------------------------------------
__global__ __launch_bounds__(256) void scan_kernel(
    const float* __restrict__ dt, const float* __restrict__ xc,
    const float* __restrict__ dbl, const float* __restrict__ A_log,
    float* __restrict__ y) {
  const int tid = threadIdx.x;
  const int n = tid & 15;
  const int dloc = tid >> 4;
  const int b = blockIdx.x >> 7;
  const int d = ((blockIdx.x & 127) << 4) + dloc;
  const float A = -__expf(A_log[(size_t)d * 16 + n]);
  float h = 0.f;
  const size_t tb = (size_t)b * 2048;
  const float* dtp = dt + tb * 2048 + d;
  const float* xcp = xc + tb * 2048 + d;
  const float* Bp = dbl + tb * 96 + 64 + n;
  const float* Cp = dbl + tb * 96 + 80 + n;
  float* yo = y + tb * 2048 + d;

  constexpr int CH = 8;
  float cdt[CH], cx[CH], cB[CH], cC[CH];
#pragma unroll
  for (int j = 0; j < CH; ++j) {
    cdt[j] = dtp[(size_t)j * 2048];
    cx[j] = xcp[(size_t)j * 2048];
    cB[j] = Bp[(size_t)j * 96];
    cC[j] = Cp[(size_t)j * 96];
  }
  for (int t0 = 0; t0 < 2048; t0 += CH) {
    float ndt[CH], nx[CH], nB[CH], nC[CH];
    const bool more = (t0 + CH < 2048);
    if (more) {
#pragma unroll
      for (int j = 0; j < CH; ++j) {
        size_t o = (size_t)(t0 + CH + j);
        ndt[j] = dtp[o * 2048];
        nx[j] = xcp[o * 2048];
        nB[j] = Bp[o * 96];
        nC[j] = Cp[o * 96];
      }
    }
#pragma unroll
    for (int j = 0; j < CH; ++j) {
      float dA = __expf(cdt[j] * A);
      h = fmaf(dA, h, cdt[j] * cx[j] * cB[j]);
      float p = h * cC[j];
      p += __shfl_xor(p, 1);
      p += __shfl_xor(p, 2);
      p += __shfl_xor(p, 4);
      p += __shfl_xor(p, 8);
      if (n == 0) yo[(size_t)(t0 + j) * 2048] = p;
    }
    if (more) {
#pragma unroll
      for (int j = 0; j < CH; ++j) {
        cdt[j] = ndt[j]; cx[j] = nx[j]; cB[j] = nB[j]; cC[j] = nC[j];
      }
    }
  }
}

// ---- y = (y + xc*D) * silu(z), emit bf16 hi/lo split (swizzled) -----------
__global__ __launch_bounds__(256) void ypost_split_kernel(
    const float* __restrict__ y, const float* __restrict__ xc,
    const float* __restrict__ xz, const float* __restrict__ Dskip,
    unsigned short* __restrict__ yh, unsigned short* __restrict__ yl) {
  const size_t idx = ((size_t)blockIdx.x * 256 + threadIdx.x) * 4;
  const size_t t = idx >> 11;
  const int d = (int)(idx & 2047);
  float4 yv = *(const float4*)(y + idx);
  float4 xv = *(const float4*)(xc + idx);
  float4 zv = *(const float4*)(xz + t * 4096 + 2048 + d);
  float4 Dv = *(const float4*)(Dskip + d);
  float yy[4] = {yv.x, yv.y, yv.z, yv.w};
  float xx[4] = {xv.x, xv.y, xv.z, xv.w};
  float zz[4] = {zv.x, zv.y, zv.z, zv.w};
  float dd[4] = {Dv.x, Dv.y, Dv.z, Dv.w};
  unsigned short hs[4], ls[4];
#pragma unroll
  for (int i = 0; i < 4; ++i) {
    float t1 = fmaf(xx[i], dd[i], yy[i]);
    float r = t1 * (zz[i] * sigmoidf_(zz[i]));
    unsigned short h = f2bf(r);
    hs[i] = h;
    ls[i] = f2bf(r - bf2f(h));
  }
  const int key = ((int)t >> 1) & 3;
  const size_t o = t * 2048 + (size_t)(d & ~31) +
                   (size_t)((((d >> 3) & 3) ^ key) << 3) + (size_t)(d & 7);
  *(ushort4*)(yh + o) = make_ushort4(hs[0], hs[1], hs[2], hs[3]);
  *(ushort4*)(yl + o) = make_ushort4(ls[0], ls[1], ls[2], ls[3]);
}

// ---------------------------------------------------------------------------
extern "C" void kernel_launch(void* const* d_in, const int* in_sizes, int n_in,
                              void* d_out, int out_size, void* d_ws,
                              size_t ws_size, hipStream_t stream) {
  const int* x = (const int*)d_in[0];
  const float* emb = (const float*)d_in[1];
  const float* W_in = (const float*)d_in[2];
  const float* conv_w = (const float*)d_in[3];
  const float* conv_b = (const float*)d_in[4];
  const float* W_x = (const float*)d_in[5];
  const float* W_dt = (const float*)d_in[6];
  const float* b_dt = (const float*)d_in[7];
  const float* A_log = (const float*)d_in[8];
  const float* D_skip = (const float*)d_in[9];
  const float* W_out = (const float*)d_in[10];
  const float* W_head = (const float*)d_in[11];
  const float* b_head = (const float*)d_in[12];
  float* out = (float*)d_out;

  float* ws = (float*)d_ws;
  float* xz = ws;                          // 16,777,216
  float* xc = ws + 16777216;               //  8,388,608
  float* dbl = ws + 25165824;              //    393,216
  float* dt = ws + 25559040;               //  8,388,608
  float* y = ws + 33947648;                //  8,388,608
  float* mo = ws + 42336256;               //  4,194,304
  // phase A (aliases y region; dead before scan writes y)
  unsigned short* tokh = (unsigned short*)(ws + 33947648);
  unsigned short* tokl = (unsigned short*)(ws + 36044800);
  unsigned short* WiTh = (unsigned short*)(ws + 38141952);
  unsigned short* WiTl = (unsigned short*)(ws + 40239104);
  // phase C (aliases dbl/dt, dead after scan)
  unsigned short* yh = (unsigned short*)(ws + 25165824);
  unsigned short* yl = (unsigned short*)(ws + 29360128);
  // WoT aliases xz (dead after ypost)
  unsigned short* WoTh = (unsigned short*)(ws + 0);
  unsigned short* WoTl = (unsigned short*)(ws + 1048576);
  // phase E (after mout): Wt aliases xz..yh/yl; mo_hi/lo alias y
  unsigned short* Wt_hi = (unsigned short*)(ws + 0);
  unsigned short* Wt_lo = (unsigned short*)(ws + 16449536);
  unsigned short* mo_hi = (unsigned short*)(ws + 32899072);
  unsigned short* mo_lo = (unsigned short*)(ws + 34996224);

  dim3 blk(256);
  // xz = emb[x] @ W_in  (MFMA)
  tok_split_kernel<<<2048, blk, 0, stream>>>(x, emb, tokh, tokl);
  split_wT_kernel<<<dim3(16, 64), blk, 0, stream>>>(W_in, 4096, WiTh, WiTl, 1024);
  gemm_mfma_kernel<1024, 0, 32><<<1024, blk, 0, stream>>>(
      tokh, tokl, WiTh, WiTl, nullptr, xz, 4096);
  // conv -> dbl -> dt -> scan (fp32, unchanged)
  conv_silu_kernel<<<32768, blk, 0, stream>>>(xz, conv_w, conv_b, xc);
  gemm_dbl_kernel<<<384, blk, 0, stream>>>(xc, W_x, dbl);
  gemm_dt_kernel<<<8192, blk, 0, stream>>>(dbl, W_dt, b_dt, dt);
  scan_kernel<<<256, blk, 0, stream>>>(dt, xc, dbl, A_log, y);
  // gating + split of y
  ypost_split_kernel<<<8192, blk, 0, stream>>>(y, xc, xz, D_skip, yh, yl);
  // mo = y @ W_out  (MFMA)
  split_wT_kernel<<<dim3(32, 16), blk, 0, stream>>>(W_out, 1024, WoTh, WoTl, 2048);
  gemm_mfma_kernel<2048, 0, 8><<<256, blk, 0, stream>>>(
      yh, yl, WoTh, WoTl, nullptr, mo, 1024);
  // head (MFMA): W_head split must come after mout (aliases yh/yl region)
  split_wT_kernel<<<dim3(16, 502), blk, 0, stream>>>(W_head, 32002, Wt_hi, Wt_lo, 1024);
  split_mo_kernel<<<2048, blk, 0, stream>>>(mo, mo_hi, mo_lo);
  gemm_mfma_kernel<1024, 1, 32><<<8032, blk, 0, stream>>>(
      Wt_hi, Wt_lo, mo_hi, mo_lo, b_head, out, 2048);
}

// Round 3
// 2070.710 us; speedup vs baseline: 1.3486x; 1.1268x over previous
//
#include <hip/hip_runtime.h>
#include <cstddef>
#include <cstdint>

// ---------------------------------------------------------------------------
// Mamba forward. T = B*L = 4096 tokens. D_MODEL=1024, D_INNER=2048,
// DT_RANK=64, N_STATE=16, V2=32002.
//
// GEMMs on MFMA via 3-term bf16 split (ah*bh + ah*bl + al*bh).
// head + xz: 256x256 8-phase schedule (T3+T4+T5). mout: 128x128 2-phase.
// Scan: 8-way chunked (local scan + serial chunk-combine + correction).
//
// Workspace (floats), total 46,530,560 = 186.1 MB, lifetime-aliased:
//   xz   [4096x4096] fp32 @ 0
//   xc   [4096x2048] fp32 @ 16,777,216
//   dbl  [4096x96]   fp32 @ 25,165,824
//   dt   [4096x2048] fp32 @ 25,559,040
//   y    [4096x2048] fp32 @ 33,947,648
//   mo   [4096x1024] fp32 @ 42,336,256
// phase A (in y region, dead before scan):
//   tokh/tokl @ 33,947,648 / 36,044,800 ; WiTh/WiTl @ 38,141,952 / 40,239,104
// scan temps (in mo region, dead before mout): hend @ 42,336,256 (524,288),
//   send @ 42,860,544 (32,768)
// phase C (after scan, alias dbl/dt): yh @ 25,165,824, yl @ 29,360,128
//   WoTh/WoTl @ 0 / 1,048,576 (alias xz)
// phase E (after mout): Wt_hi @ 0, Wt_lo @ 16,515,072 (32256x1024 each),
//   mo_hi @ 33,554,432, mo_lo @ 35,651,584
// ---------------------------------------------------------------------------

typedef __bf16 bf16x8 __attribute__((ext_vector_type(8)));
typedef float f32x4 __attribute__((ext_vector_type(4)));

__device__ __forceinline__ float sigmoidf_(float x) {
  return 1.0f / (1.0f + __expf(-x));
}

__device__ __forceinline__ unsigned short f2bf(float v) {
  unsigned u = __float_as_uint(v);
  u += 0x7fffu + ((u >> 16) & 1u);
  return (unsigned short)(u >> 16);
}
__device__ __forceinline__ float bf2f(unsigned short h) {
  return __uint_as_float(((unsigned)h) << 16);
}

__device__ __forceinline__ void gload_lds16(const void* g, void* l) {
  typedef const unsigned int GQ __attribute__((address_space(1)));
  typedef unsigned int LQ __attribute__((address_space(3)));
  __builtin_amdgcn_global_load_lds((GQ*)(unsigned long long)g,
                                   (LQ*)(unsigned)(unsigned long long)l,
                                   16, 0, 0);
}

__device__ __forceinline__ f32x4 mfma16(bf16x8 a, bf16x8 b, f32x4 c) {
  return __builtin_amdgcn_mfma_f32_16x16x32_bf16(a, b, c, 0, 0, 0);
}

// ---------------- generic: W [K][Nreal] -> hi/lo [Npad][K] swizzled --------
__global__ __launch_bounds__(256) void split_wT_kernel(
    const float* __restrict__ W, int Nreal, unsigned short* __restrict__ hi,
    unsigned short* __restrict__ lo, int K) {
  __shared__ float tile[64][65];
  const int k0 = blockIdx.x * 64, n0 = blockIdx.y * 64;
  const int tq = threadIdx.x >> 6;
  const int tl = threadIdx.x & 63;
#pragma unroll
  for (int r = 0; r < 16; ++r) {
    int kk = r * 4 + tq;
    int n = n0 + tl;
    tile[kk][tl] = (n < Nreal) ? W[(size_t)(k0 + kk) * Nreal + n] : 0.f;
  }
  __syncthreads();
#pragma unroll
  for (int r = 0; r < 16; ++r) {
    int nn = r * 4 + tq;
    int n = n0 + nn;
    int k = k0 + tl;
    float v = tile[tl][nn];
    unsigned short h = f2bf(v);
    unsigned short l = f2bf(v - bf2f(h));
    int key = (n >> 1) & 3;
    size_t o = (size_t)n * K + (size_t)(k & ~31) +
               (size_t)(((((k >> 3) & 3) ^ key)) << 3) + (size_t)(k & 7);
    hi[o] = h;
    lo[o] = l;
  }
}

// ---------------- token gather + bf16 split + swizzle ----------------------
__global__ __launch_bounds__(256) void tok_split_kernel(
    const int* __restrict__ x, const float* __restrict__ emb,
    unsigned short* __restrict__ th, unsigned short* __restrict__ tlo) {
  const int i = blockIdx.x * 256 + threadIdx.x;
  const int t = i >> 7;
  const int sb = i & 127;
  const int row = x[t];
  const float* src = emb + (size_t)row * 1024 + (size_t)sb * 8;
  float4 v0 = *(const float4*)(src);
  float4 v1 = *(const float4*)(src + 4);
  float vv[8] = {v0.x, v0.y, v0.z, v0.w, v1.x, v1.y, v1.z, v1.w};
  unsigned hu[4], lu[4];
#pragma unroll
  for (int j = 0; j < 4; ++j) {
    unsigned short h0 = f2bf(vv[2 * j]), h1 = f2bf(vv[2 * j + 1]);
    unsigned short l0 = f2bf(vv[2 * j] - bf2f(h0));
    unsigned short l1 = f2bf(vv[2 * j + 1] - bf2f(h1));
    hu[j] = (unsigned)h0 | ((unsigned)h1 << 16);
    lu[j] = (unsigned)l0 | ((unsigned)l1 << 16);
  }
  const int key = (t >> 1) & 3;
  const int sdst = (sb & 3) ^ key;
  size_t o = (size_t)t * 1024 + (size_t)(sb >> 2) * 32 + (size_t)sdst * 8;
  *(uint4*)(th + o) = make_uint4(hu[0], hu[1], hu[2], hu[3]);
  *(uint4*)(tlo + o) = make_uint4(lu[0], lu[1], lu[2], lu[3]);
}

// ---------------- split mo: bf16 hi/lo + swizzle ---------------------------
__global__ __launch_bounds__(256) void split_mo_kernel(
    const float* __restrict__ mo, unsigned short* __restrict__ mhi,
    unsigned short* __restrict__ mlo) {
  const int i = blockIdx.x * 256 + threadIdx.x;
  const int t = i >> 7;
  const int sb = i & 127;
  const float* src = mo + (size_t)t * 1024 + (size_t)sb * 8;
  float4 v0 = *(const float4*)(src);
  float4 v1 = *(const float4*)(src + 4);
  float vv[8] = {v0.x, v0.y, v0.z, v0.w, v1.x, v1.y, v1.z, v1.w};
  unsigned hu[4], lu[4];
#pragma unroll
  for (int j = 0; j < 4; ++j) {
    unsigned short h0 = f2bf(vv[2 * j]), h1 = f2bf(vv[2 * j + 1]);
    unsigned short l0 = f2bf(vv[2 * j] - bf2f(h0));
    unsigned short l1 = f2bf(vv[2 * j + 1] - bf2f(h1));
    hu[j] = (unsigned)h0 | ((unsigned)h1 << 16);
    lu[j] = (unsigned)l0 | ((unsigned)l1 << 16);
  }
  const int key = (t >> 1) & 3;
  const int sdst = (sb & 3) ^ key;
  size_t o = (size_t)t * 1024 + (size_t)(sb >> 2) * 32 + (size_t)sdst * 8;
  *(uint4*)(mhi + o) = make_uint4(hu[0], hu[1], hu[2], hu[3]);
  *(uint4*)(mlo + o) = make_uint4(lu[0], lu[1], lu[2], lu[3]);
}

// ---------------- 256x256 8-phase MFMA GEMM, 3-term bf16 split -------------
// D[row][col] = sum_k A[row][k]*B[col][k]. 8 waves (2M x 4N), BK=32,
// 4 phases/K-step, double-buffered LDS (128 KiB), setprio around MFMA.
// OUTMODE 0: out[row*ldo+col]. OUTMODE 1: head layout + bias + guard.
template <int K, int OUTMODE, int CT>
__global__ __launch_bounds__(512, 2) void gemm256_kernel(
    const unsigned short* __restrict__ Ah_, const unsigned short* __restrict__ Al_,
    const unsigned short* __restrict__ Bh_, const unsigned short* __restrict__ Bl_,
    const float* __restrict__ bias, float* __restrict__ out, int ldo) {
  __shared__ unsigned short sAh[2][8192], sAl[2][8192];
  __shared__ unsigned short sBh[2][8192], sBl[2][8192];  // 128 KiB total
  const int tid = threadIdx.x;
  const int lane = tid & 63, wid = tid >> 6;
  const int wr = wid >> 2, wc = wid & 3;  // 2M x 4N waves
  const int chunk = (int)gridDim.x >> 3;
  const int swz = ((blockIdx.x & 7) * chunk) + (blockIdx.x >> 3);
  const int R0 = (swz / CT) * 256;
  const int C0 = (swz % CT) * 256;

  // staging: per array 1024 chunks of 8 elems; thread t -> chunks t, t+512.
  const int rr = tid >> 2, ss = (tid & 3) * 8;
  const unsigned short* gAh0 = Ah_ + (size_t)(R0 + rr) * K + ss;
  const unsigned short* gAl0 = Al_ + (size_t)(R0 + rr) * K + ss;
  const unsigned short* gBh0 = Bh_ + (size_t)(C0 + rr) * K + ss;
  const unsigned short* gBl0 = Bl_ + (size_t)(C0 + rr) * K + ss;
  const unsigned short* gAh1 = gAh0 + (size_t)128 * K;
  const unsigned short* gAl1 = gAl0 + (size_t)128 * K;
  const unsigned short* gBh1 = gBh0 + (size_t)128 * K;
  const unsigned short* gBl1 = gBl0 + (size_t)128 * K;
  const int l0 = tid * 8, l1 = tid * 8 + 4096;

#define STAGE256(BUF, KOFF)                      \
  do {                                           \
    gload_lds16(gAh0 + (KOFF), &sAh[BUF][l0]);   \
    gload_lds16(gAh1 + (KOFF), &sAh[BUF][l1]);   \
    gload_lds16(gAl0 + (KOFF), &sAl[BUF][l0]);   \
    gload_lds16(gAl1 + (KOFF), &sAl[BUF][l1]);   \
    gload_lds16(gBh0 + (KOFF), &sBh[BUF][l0]);   \
    gload_lds16(gBh1 + (KOFF), &sBh[BUF][l1]);   \
    gload_lds16(gBl0 + (KOFF), &sBl[BUF][l0]);   \
    gload_lds16(gBl1 + (KOFF), &sBl[BUF][l1]);   \
  } while (0)

  // fragment LDS offsets (XOR matches global pre-swizzle)
  const int fr = lane & 15;
  const int kb = (lane >> 4) * 8;
  int aoff[8], boff[4];
#pragma unroll
  for (int m = 0; m < 8; ++m) {
    int r = 128 * wr + 16 * m + fr;
    aoff[m] = r * 32 + (kb ^ (((r >> 1) & 3) << 3));
  }
#pragma unroll
  for (int nf = 0; nf < 4; ++nf) {
    int r = 64 * wc + 16 * nf + fr;
    boff[nf] = r * 32 + (kb ^ (((r >> 1) & 3) << 3));
  }

  f32x4 acc[8][4];
#pragma unroll
  for (int m = 0; m < 8; ++m)
#pragma unroll
    for (int nf = 0; nf < 4; ++nf) acc[m][nf] = f32x4{0.f, 0.f, 0.f, 0.f};

  STAGE256(0, 0);
  constexpr int KSTEPS = K / 32;
  for (int ks = 0; ks < KSTEPS; ++ks) {
    const int cur = ks & 1;
    __syncthreads();  // drains vmcnt+lgkm: buf[cur] staged & prev reads done
    bf16x8 bh[4], bl[4];
#pragma unroll
    for (int p = 0; p < 4; ++p) {
      bf16x8 a0h = *(const bf16x8*)&sAh[cur][aoff[2 * p]];
      bf16x8 a0l = *(const bf16x8*)&sAl[cur][aoff[2 * p]];
      bf16x8 a1h = *(const bf16x8*)&sAh[cur][aoff[2 * p + 1]];
      bf16x8 a1l = *(const bf16x8*)&sAl[cur][aoff[2 * p + 1]];
      if (p == 0) {
#pragma unroll
        for (int nf = 0; nf < 4; ++nf) {
          bh[nf] = *(const bf16x8*)&sBh[cur][boff[nf]];
          bl[nf] = *(const bf16x8*)&sBl[cur][boff[nf]];
        }
        if (ks + 1 < KSTEPS) STAGE256(cur ^ 1, (ks + 1) * 32);
      }
      __builtin_amdgcn_s_barrier();
      __builtin_amdgcn_s_setprio(1);
#pragma unroll
      for (int nf = 0; nf < 4; ++nf) {
        acc[2 * p][nf] = mfma16(a0h, bh[nf], acc[2 * p][nf]);
        acc[2 * p][nf] = mfma16(a0h, bl[nf], acc[2 * p][nf]);
        acc[2 * p][nf] = mfma16(a0l, bh[nf], acc[2 * p][nf]);
        acc[2 * p + 1][nf] = mfma16(a1h, bh[nf], acc[2 * p + 1][nf]);
        acc[2 * p + 1][nf] = mfma16(a1h, bl[nf], acc[2 * p + 1][nf]);
        acc[2 * p + 1][nf] = mfma16(a1l, bh[nf], acc[2 * p + 1][nf]);
      }
      __builtin_amdgcn_s_setprio(0);
      __builtin_amdgcn_s_barrier();
    }
  }
#undef STAGE256

  // C/D layout: col = lane&15 (B rows), row = 4*(lane>>4)+reg (A rows).
  const int frow = 4 * (lane >> 4);
#pragma unroll
  for (int m = 0; m < 8; ++m) {
    const int gr_base = R0 + 128 * wr + 16 * m + frow;
#pragma unroll
    for (int r = 0; r < 4; ++r) {
      const int gr = gr_base + r;
      if constexpr (OUTMODE == 1) {
        if (gr < 32002) {
          const float bb = bias[gr];
#pragma unroll
          for (int nf = 0; nf < 4; ++nf) {
            const int gc = C0 + 64 * wc + 16 * nf + fr;
            const int b_idx = gc >> 11;
            const int l = gc & 2047;
            out[((size_t)b_idx * 32002 + gr) * 2048 + l] = acc[m][nf][r] + bb;
          }
        }
      } else {
#pragma unroll
        for (int nf = 0; nf < 4; ++nf) {
          const int gc = C0 + 64 * wc + 16 * nf + fr;
          out[(size_t)gr * ldo + gc] = acc[m][nf][r];
        }
      }
    }
  }
}

// ---------------- 128x128 2-phase MFMA GEMM (kept for mout) ----------------
template <int K, int OUTMODE, int BT>
__global__ __launch_bounds__(256, 2) void gemm_mfma_kernel(
    const unsigned short* __restrict__ Ah_, const unsigned short* __restrict__ Al_,
    const unsigned short* __restrict__ Bh_, const unsigned short* __restrict__ Bl_,
    const float* __restrict__ bias, float* __restrict__ out, int ldo) {
  __shared__ unsigned short Ah[4096], Al[4096], Bh[4096], Bl[4096];
  const int tid = threadIdx.x;
  const int lane = tid & 63, wid = tid >> 6;
  const int wr = wid >> 1, wc = wid & 1;
  const int chunk = (int)gridDim.x >> 3;
  const int swz = ((blockIdx.x & 7) * chunk) + (blockIdx.x >> 3);
  const int R0 = (swz / BT) * 128;
  const int C0 = (swz % BT) * 128;

  const int c0 = tid, c1 = tid + 256;
  const int r0 = c0 >> 2, s0 = (c0 & 3) * 8;
  const int r1 = c1 >> 2, s1 = (c1 & 3) * 8;
  const unsigned short* pA0h = Ah_ + (size_t)(R0 + r0) * K + s0;
  const unsigned short* pA0l = Al_ + (size_t)(R0 + r0) * K + s0;
  const unsigned short* pB0h = Bh_ + (size_t)(C0 + r0) * K + s0;
  const unsigned short* pB0l = Bl_ + (size_t)(C0 + r0) * K + s0;
  const unsigned short* pA1h = Ah_ + (size_t)(R0 + r1) * K + s1;
  const unsigned short* pA1l = Al_ + (size_t)(R0 + r1) * K + s1;
  const unsigned short* pB1h = Bh_ + (size_t)(C0 + r1) * K + s1;
  const unsigned short* pB1l = Bl_ + (size_t)(C0 + r1) * K + s1;
  unsigned short* lA0 = Ah + c0 * 8;
  unsigned short* lA1 = Ah + c1 * 8;
  unsigned short* lAl0 = Al + c0 * 8;
  unsigned short* lAl1 = Al + c1 * 8;
  unsigned short* lB0 = Bh + c0 * 8;
  unsigned short* lB1 = Bh + c1 * 8;
  unsigned short* lBl0 = Bl + c0 * 8;
  unsigned short* lBl1 = Bl + c1 * 8;

#define STAGE_T(KOFF)                 \
  do {                                \
    gload_lds16(pA0h + (KOFF), lA0);  \
    gload_lds16(pA1h + (KOFF), lA1);  \
    gload_lds16(pA0l + (KOFF), lAl0); \
    gload_lds16(pA1l + (KOFF), lAl1); \
    gload_lds16(pB0h + (KOFF), lB0);  \
    gload_lds16(pB1h + (KOFF), lB1);  \
    gload_lds16(pB0l + (KOFF), lBl0); \
    gload_lds16(pB1l + (KOFF), lBl1); \
  } while (0)

  const int fr = lane & 15;
  const int kb = (lane >> 4) * 8;
  int aoff[4], boff[4];
#pragma unroll
  for (int m = 0; m < 4; ++m) {
    int r = 64 * wr + 16 * m + fr;
    aoff[m] = r * 32 + (kb ^ (((r >> 1) & 3) << 3));
  }
#pragma unroll
  for (int nf = 0; nf < 4; ++nf) {
    int r = 64 * wc + 16 * nf + fr;
    boff[nf] = r * 32 + (kb ^ (((r >> 1) & 3) << 3));
  }

  f32x4 acc[4][4];
#pragma unroll
  for (int m = 0; m < 4; ++m)
#pragma unroll
    for (int nf = 0; nf < 4; ++nf) acc[m][nf] = f32x4{0.f, 0.f, 0.f, 0.f};

  STAGE_T(0);
  int koff = 32;
  constexpr int KSTEPS = K / 32;
  for (int ks = 0; ks < KSTEPS; ++ks) {
    __syncthreads();
    bf16x8 ah[4], al[4], bh[4], bl[4];
#pragma unroll
    for (int m = 0; m < 4; ++m) {
      ah[m] = *(const bf16x8*)(Ah + aoff[m]);
      al[m] = *(const bf16x8*)(Al + aoff[m]);
    }
#pragma unroll
    for (int nf = 0; nf < 4; ++nf) {
      bh[nf] = *(const bf16x8*)(Bh + boff[nf]);
      bl[nf] = *(const bf16x8*)(Bl + boff[nf]);
    }
    __syncthreads();
    if (ks < KSTEPS - 1) {
      STAGE_T(koff);
      koff += 32;
    }
#pragma unroll
    for (int m = 0; m < 4; ++m)
#pragma unroll
      for (int nf = 0; nf < 4; ++nf) {
        acc[m][nf] = mfma16(ah[m], bh[nf], acc[m][nf]);
        acc[m][nf] = mfma16(ah[m], bl[nf], acc[m][nf]);
        acc[m][nf] = mfma16(al[m], bh[nf], acc[m][nf]);
      }
  }
#undef STAGE_T

  const int frow = 4 * (lane >> 4);
#pragma unroll
  for (int m = 0; m < 4; ++m) {
    const int gr_base = R0 + 64 * wr + 16 * m + frow;
#pragma unroll
    for (int r = 0; r < 4; ++r) {
      const int gr = gr_base + r;
      if constexpr (OUTMODE == 1) {
        if (gr < 32002) {
          const float bb = bias[gr];
#pragma unroll
          for (int nf = 0; nf < 4; ++nf) {
            const int gc = C0 + 64 * wc + 16 * nf + fr;
            const int b_idx = gc >> 11;
            const int l = gc & 2047;
            out[((size_t)b_idx * 32002 + gr) * 2048 + l] = acc[m][nf][r] + bb;
          }
        }
      } else {
#pragma unroll
        for (int nf = 0; nf < 4; ++nf) {
          const int gc = C0 + 64 * wc + 16 * nf + fr;
          out[(size_t)gr * ldo + gc] = acc[m][nf][r];
        }
      }
    }
  }
}

// ---------------- depthwise causal conv (taps=4) + SiLU --------------------
__global__ __launch_bounds__(256) void conv_silu_kernel(
    const float* __restrict__ xz, const float* __restrict__ conv_w,
    const float* __restrict__ conv_b, float* __restrict__ xc) {
  const int idx = blockIdx.x * 256 + threadIdx.x;
  const int t = idx >> 11, d = idx & 2047;
  const int l = t & 2047;
  const float4 w = *(const float4*)(conv_w + (size_t)d * 4);
  const float ww[4] = {w.x, w.y, w.z, w.w};
  float s = conv_b[d];
  const float* xm = xz + d;
#pragma unroll
  for (int j = 0; j < 4; ++j) {
    int lj = l - 3 + j;
    if (lj >= 0) s = fmaf(ww[j], xm[(size_t)(t - 3 + j) * 4096], s);
  }
  xc[idx] = s * sigmoidf_(s);
}

// ---------------- dbl = xc @ W_x   M=4096 K=2048 N=96 ----------------------
__global__ __launch_bounds__(256) void gemm_dbl_kernel(
    const float* __restrict__ xc, const float* __restrict__ Wx,
    float* __restrict__ dbl) {
  const int idx = blockIdx.x * 256 + threadIdx.x;
  const int tq = idx / 96, c = idx % 96;
  const size_t t0 = (size_t)tq * 4;
  const float* a0 = xc + t0 * 2048;
  float acc[4] = {0.f, 0.f, 0.f, 0.f};
  for (int k = 0; k < 2048; k += 4) {
    float w0 = Wx[(size_t)(k + 0) * 96 + c];
    float w1 = Wx[(size_t)(k + 1) * 96 + c];
    float w2 = Wx[(size_t)(k + 2) * 96 + c];
    float w3 = Wx[(size_t)(k + 3) * 96 + c];
#pragma unroll
    for (int i = 0; i < 4; ++i) {
      float4 avv = *(const float4*)(a0 + (size_t)i * 2048 + k);
      acc[i] = fmaf(avv.x, w0, acc[i]);
      acc[i] = fmaf(avv.y, w1, acc[i]);
      acc[i] = fmaf(avv.z, w2, acc[i]);
      acc[i] = fmaf(avv.w, w3, acc[i]);
    }
  }
#pragma unroll
  for (int i = 0; i < 4; ++i) dbl[(t0 + i) * 96 + c] = acc[i];
}

// ---------------- dt = softplus(dt_r @ W_dt + b_dt)  K=64 N=2048 -----------
__global__ __launch_bounds__(256) void gemm_dt_kernel(
    const float* __restrict__ dbl, const float* __restrict__ Wdt,
    const float* __restrict__ b_dt, float* __restrict__ dt) {
  __shared__ float s[4][64];
  const int t0 = (blockIdx.x >> 3) * 4;
  const int d = ((blockIdx.x & 7) << 8) + threadIdx.x;
  {
    int tt = threadIdx.x >> 6, k = threadIdx.x & 63;
    s[tt][k] = dbl[(size_t)(t0 + tt) * 96 + k];
  }
  __syncthreads();
  const float bd = b_dt[d];
  float acc[4] = {bd, bd, bd, bd};
#pragma unroll 16
  for (int k = 0; k < 64; ++k) {
    float w = Wdt[(size_t)k * 2048 + d];
#pragma unroll
    for (int i = 0; i < 4; ++i) acc[i] = fmaf(s[i][k], w, acc[i]);
  }
#pragma unroll
  for (int i = 0; i < 4; ++i) {
    float v = acc[i];
    float sp = (v > 20.f) ? v : log1pf(__expf(v));
    dt[(size_t)(t0 + i) * 2048 + d] = sp;
  }
}

// ---------------- chunked selective scan: pass 1 (local) -------------------
// grid 2048 = b(2) x dgrp(128) x chunk(8); each block scans 256 steps with
// h0 = 0; writes y_local, chunk-end h, and sum(dt) over chunk.
__global__ __launch_bounds__(256) void scan_local_kernel(
    const float* __restrict__ dt, const float* __restrict__ xc,
    const float* __restrict__ dbl, const float* __restrict__ A_log,
    float* __restrict__ y, float* __restrict__ hend, float* __restrict__ send) {
  const int tid = threadIdx.x;
  const int n = tid & 15;
  const int dloc = tid >> 4;
  const int c = blockIdx.x & 7;
  const int dg = (blockIdx.x >> 3) & 127;
  const int b = blockIdx.x >> 10;
  const int d = dg * 16 + dloc;
  const float A = -__expf(A_log[(size_t)d * 16 + n]);
  float h = 0.f, sdt = 0.f;
  const size_t trow = (size_t)b * 2048 + (size_t)c * 256;
  const float* dtp = dt + trow * 2048 + d;
  const float* xcp = xc + trow * 2048 + d;
  const float* Bp = dbl + trow * 96 + 64 + n;
  const float* Cp = dbl + trow * 96 + 80 + n;
  float* yo = y + trow * 2048 + d;

  constexpr int CH = 8;
  float cdt[CH], cx[CH], cB[CH], cC[CH];
#pragma unroll
  for (int j = 0; j < CH; ++j) {
    cdt[j] = dtp[(size_t)j * 2048];
    cx[j] = xcp[(size_t)j * 2048];
    cB[j] = Bp[(size_t)j * 96];
    cC[j] = Cp[(size_t)j * 96];
  }
  for (int t0 = 0; t0 < 256; t0 += CH) {
    float ndt[CH], nx[CH], nB[CH], nC[CH];
    const bool more = (t0 + CH < 256);
    if (more) {
#pragma unroll
      for (int j = 0; j < CH; ++j) {
        size_t o = (size_t)(t0 + CH + j);
        ndt[j] = dtp[o * 2048];
        nx[j] = xcp[o * 2048];
        nB[j] = Bp[o * 96];
        nC[j] = Cp[o * 96];
      }
    }
#pragma unroll
    for (int j = 0; j < CH; ++j) {
      float dA = __expf(cdt[j] * A);
      h = fmaf(dA, h, cdt[j] * cx[j] * cB[j]);
      sdt += cdt[j];
      float p = h * cC[j];
      p += __shfl_xor(p, 1);
      p += __shfl_xor(p, 2);
      p += __shfl_xor(p, 4);
      p += __shfl_xor(p, 8);
      if (n == 0) yo[(size_t)(t0 + j) * 2048] = p;
    }
    if (more) {
#pragma unroll
      for (int j = 0; j < CH; ++j) {
        cdt[j] = ndt[j]; cx[j] = nx[j]; cB[j] = nB[j]; cC[j] = nC[j];
      }
    }
  }
  hend[(((size_t)b * 8 + c) * 2048 + d) * 16 + n] = h;
  if (n == 0) send[((size_t)b * 8 + c) * 2048 + d] = sdt;
}

// ---------------- chunked selective scan: pass 2 (correction) --------------
// carry G = global h at end of chunk c-1 (serial combine over <=7 chunks);
// y[t] += C_t . (exp(A*cumdt_t) * G).
__global__ __launch_bounds__(256) void scan_fix_kernel(
    const float* __restrict__ dt, const float* __restrict__ dbl,
    const float* __restrict__ A_log, const float* __restrict__ hend,
    const float* __restrict__ send, float* __restrict__ y) {
  const int c = blockIdx.x & 7;
  if (c == 0) return;
  const int tid = threadIdx.x;
  const int n = tid & 15;
  const int dloc = tid >> 4;
  const int dg = (blockIdx.x >> 3) & 127;
  const int b = blockIdx.x >> 10;
  const int d = dg * 16 + dloc;
  const float A = -__expf(A_log[(size_t)d * 16 + n]);
  float G = 0.f;
  for (int cp = 0; cp < c; ++cp) {
    float P = __expf(A * send[((size_t)b * 8 + cp) * 2048 + d]);
    G = fmaf(P, G, hend[(((size_t)b * 8 + cp) * 2048 + d) * 16 + n]);
  }
  const size_t trow = (size_t)b * 2048 + (size_t)c * 256;
  const float* dtp = dt + trow * 2048 + d;
  const float* Cp = dbl + trow * 96 + 80 + n;
  float* yo = y + trow * 2048 + d;
  float cum = 0.f;

  constexpr int CH = 8;
  float cdt[CH], cC[CH];
#pragma unroll
  for (int j = 0; j < CH; ++j) {
    cdt[j] = dtp[(size_t)j * 2048];
    cC[j] = Cp[(size_t)j * 96];
  }
  for (int t0 = 0; t0 < 256; t0 += CH) {
    float ndt[CH], nC[CH];
    const bool more = (t0 + CH < 256);
    if (more) {
#pragma unroll
      for (int j = 0; j < CH; ++j) {
        size_t o = (size_t)(t0 + CH + j);
        ndt[j] = dtp[o * 2048];
        nC[j] = Cp[o * 96];
      }
    }
#pragma unroll
    for (int j = 0; j < CH; ++j) {
      cum += cdt[j];
      float p = __expf(A * cum) * G * cC[j];
      p += __shfl_xor(p, 1);
      p += __shfl_xor(p, 2);
      p += __shfl_xor(p, 4);
      p += __shfl_xor(p, 8);
      if (n == 0) yo[(size_t)(t0 + j) * 2048] += p;
    }
    if (more) {
#pragma unroll
      for (int j = 0; j < CH; ++j) {
        cdt[j] = ndt[j]; cC[j] = nC[j];
      }
    }
  }
}

// ---- y = (y + xc*D) * silu(z), emit bf16 hi/lo split (swizzled) -----------
__global__ __launch_bounds__(256) void ypost_split_kernel(
    const float* __restrict__ y, const float* __restrict__ xc,
    const float* __restrict__ xz, const float* __restrict__ Dskip,
    unsigned short* __restrict__ yh, unsigned short* __restrict__ yl) {
  const size_t idx = ((size_t)blockIdx.x * 256 + threadIdx.x) * 4;
  const size_t t = idx >> 11;
  const int d = (int)(idx & 2047);
  float4 yv = *(const float4*)(y + idx);
  float4 xv = *(const float4*)(xc + idx);
  float4 zv = *(const float4*)(xz + t * 4096 + 2048 + d);
  float4 Dv = *(const float4*)(Dskip + d);
  float yy[4] = {yv.x, yv.y, yv.z, yv.w};
  float xx[4] = {xv.x, xv.y, xv.z, xv.w};
  float zz[4] = {zv.x, zv.y, zv.z, zv.w};
  float dd[4] = {Dv.x, Dv.y, Dv.z, Dv.w};
  unsigned short hs[4], ls[4];
#pragma unroll
  for (int i = 0; i < 4; ++i) {
    float t1 = fmaf(xx[i], dd[i], yy[i]);
    float r = t1 * (zz[i] * sigmoidf_(zz[i]));
    unsigned short h = f2bf(r);
    hs[i] = h;
    ls[i] = f2bf(r - bf2f(h));
  }
  const int key = ((int)t >> 1) & 3;
  const size_t o = t * 2048 + (size_t)(d & ~31) +
                   (size_t)((((d >> 3) & 3) ^ key) << 3) + (size_t)(d & 7);
  *(ushort4*)(yh + o) = make_ushort4(hs[0], hs[1], hs[2], hs[3]);
  *(ushort4*)(yl + o) = make_ushort4(ls[0], ls[1], ls[2], ls[3]);
}

// ---------------------------------------------------------------------------
extern "C" void kernel_launch(void* const* d_in, const int* in_sizes, int n_in,
                              void* d_out, int out_size, void* d_ws,
                              size_t ws_size, hipStream_t stream) {
  const int* x = (const int*)d_in[0];
  const float* emb = (const float*)d_in[1];
  const float* W_in = (const float*)d_in[2];
  const float* conv_w = (const float*)d_in[3];
  const float* conv_b = (const float*)d_in[4];
  const float* W_x = (const float*)d_in[5];
  const float* W_dt = (const float*)d_in[6];
  const float* b_dt = (const float*)d_in[7];
  const float* A_log = (const float*)d_in[8];
  const float* D_skip = (const float*)d_in[9];
  const float* W_out = (const float*)d_in[10];
  const float* W_head = (const float*)d_in[11];
  const float* b_head = (const float*)d_in[12];
  float* out = (float*)d_out;

  float* ws = (float*)d_ws;
  float* xz = ws;                          // 16,777,216
  float* xc = ws + 16777216;               //  8,388,608
  float* dbl = ws + 25165824;              //    393,216
  float* dt = ws + 25559040;               //  8,388,608
  float* y = ws + 33947648;                //  8,388,608
  float* mo = ws + 42336256;               //  4,194,304
  // phase A (aliases y region; dead before scan writes y)
  unsigned short* tokh = (unsigned short*)(ws + 33947648);
  unsigned short* tokl = (unsigned short*)(ws + 36044800);
  unsigned short* WiTh = (unsigned short*)(ws + 38141952);
  unsigned short* WiTl = (unsigned short*)(ws + 40239104);
  // scan temps (alias mo; dead before mout)
  float* hend = ws + 42336256;             // 524,288
  float* send = ws + 42860544;             //  32,768
  // phase C (aliases dbl/dt, dead after scan)
  unsigned short* yh = (unsigned short*)(ws + 25165824);
  unsigned short* yl = (unsigned short*)(ws + 29360128);
  // WoT aliases xz (dead after ypost)
  unsigned short* WoTh = (unsigned short*)(ws + 0);
  unsigned short* WoTl = (unsigned short*)(ws + 1048576);
  // phase E (after mout): Wt (32256x1024) aliases xz..yl; mo split in y region
  unsigned short* Wt_hi = (unsigned short*)(ws + 0);
  unsigned short* Wt_lo = (unsigned short*)(ws + 16515072);
  unsigned short* mo_hi = (unsigned short*)(ws + 33554432);
  unsigned short* mo_lo = (unsigned short*)(ws + 35651584);

  dim3 blk(256);
  dim3 blk512(512);
  // xz = emb[x] @ W_in  (MFMA 256^2 8-phase)
  tok_split_kernel<<<2048, blk, 0, stream>>>(x, emb, tokh, tokl);
  split_wT_kernel<<<dim3(16, 64), blk, 0, stream>>>(W_in, 4096, WiTh, WiTl, 1024);
  gemm256_kernel<1024, 0, 16><<<256, blk512, 0, stream>>>(
      tokh, tokl, WiTh, WiTl, nullptr, xz, 4096);
  // conv -> dbl -> dt
  conv_silu_kernel<<<32768, blk, 0, stream>>>(xz, conv_w, conv_b, xc);
  gemm_dbl_kernel<<<384, blk, 0, stream>>>(xc, W_x, dbl);
  gemm_dt_kernel<<<8192, blk, 0, stream>>>(dbl, W_dt, b_dt, dt);
  // chunked scan (8 chunks of 256)
  scan_local_kernel<<<2048, blk, 0, stream>>>(dt, xc, dbl, A_log, y, hend, send);
  scan_fix_kernel<<<2048, blk, 0, stream>>>(dt, dbl, A_log, hend, send, y);
  // gating + split of y
  ypost_split_kernel<<<8192, blk, 0, stream>>>(y, xc, xz, D_skip, yh, yl);
  // mo = y @ W_out  (MFMA 128^2)
  split_wT_kernel<<<dim3(32, 16), blk, 0, stream>>>(W_out, 1024, WoTh, WoTl, 2048);
  gemm_mfma_kernel<2048, 0, 8><<<256, blk, 0, stream>>>(
      yh, yl, WoTh, WoTl, nullptr, mo, 1024);
  // head (MFMA 256^2 8-phase): Wt padded to 32256 rows
  split_wT_kernel<<<dim3(16, 504), blk, 0, stream>>>(W_head, 32002, Wt_hi, Wt_lo, 1024);
  split_mo_kernel<<<2048, blk, 0, stream>>>(mo, mo_hi, mo_lo);
  gemm256_kernel<1024, 1, 16><<<2016, blk512, 0, stream>>>(
      Wt_hi, Wt_lo, mo_hi, mo_lo, b_head, out, 2048);
}